// Round 5
// baseline (229.279 us; speedup 1.0000x reference)
//
#include <hip/hip_runtime.h>
#include <math.h>

#define NWG 256
#define NPAIR 128
#define NITER 3
#define NBATCH 8192
#define KDIM 512
#define MSZ (512*512)      // elems per embedded matrix (bmat)
#define PLANE 65536        // elems per 256x256 plane
#define CMSZ (2*PLANE)     // compact complex matrix: re plane + im plane
#define NCHUNK 8           // chunks per iteration
#define CHL 32             // layers per chunk
#define PROPBLK 1536       // 24 groups * 64 blocks

typedef __attribute__((ext_vector_type(8))) short short8;
typedef __attribute__((ext_vector_type(4))) float floatx4;

static __device__ __forceinline__ unsigned short f2bf(float f) {
    unsigned int u = __float_as_uint(f);
    unsigned int r = (u + 0x7fffu + ((u >> 16) & 1u)) >> 16;
    return (unsigned short)r;
}
static __device__ __forceinline__ float bf2f(unsigned short h) {
    return __uint_as_float(((unsigned int)h) << 16);
}
static __device__ __forceinline__ void bsplit(float v, unsigned short &h, unsigned short &l) {
    h = f2bf(v);
    l = f2bf(v - bf2f(h));
}
static __device__ __forceinline__ void async16(const void* g, void* l) {
    __builtin_amdgcn_global_load_lds(
        (const __attribute__((address_space(1))) unsigned int*)g,
        (__attribute__((address_space(3))) unsigned int*)l, 16, 0, 0);
}

static __device__ __forceinline__ void apply2(
    float &x0r, float &x0i, float &x1r, float &x1i,
    const float4 a, const float4 b)
{
    float y0r = a.x*x0r - a.y*x0i + a.z*x1r - a.w*x1i;
    float y0i = a.x*x0i + a.y*x0r + a.z*x1i + a.w*x1r;
    float y1r = b.x*x0r - b.y*x0i + b.z*x1r - b.w*x1i;
    float y1i = b.x*x0i + b.y*x0r + b.z*x1i + b.w*x1r;
    x0r = y0r; x0i = y0i; x1r = y1r; x1i = y1i;
}

// coef rows (A,B),(C,D) per pair ; gexp {cos,sin}
__global__ void precompute_kernel(const float* __restrict__ theta,
                                  const float* __restrict__ phi,
                                  const float* __restrict__ gamma,
                                  float* __restrict__ coef,
                                  float* __restrict__ gexp)
{
    int idx = blockIdx.x * blockDim.x + threadIdx.x;
    if (idx < NITER * NWG * NPAIR) {
        float h  = 0.5f * theta[idx];
        float ph = phi[idx];
        float sh = sinf(h),  ch = cosf(h);
        float sp = sinf(ph), cp = cosf(ph);
        float pr = -sh, pii = ch;            // pre = i*exp(i*h)
        float qr = pr*cp - pii*sp;           // pre*exp(i*ph)
        float qi = pr*sp + pii*cp;
        float4* o = (float4*)coef + (size_t)idx * 2;
        o[0] = make_float4(qr*sh,  qi*sh,  pr*ch,  pii*ch);   // A,B
        o[1] = make_float4(qr*ch,  qi*ch, -pr*sh, -pii*sh);   // C,D
    }
    if (idx < NITER * NWG) {
        float g = gamma[idx];
        gexp[idx*2]   = cosf(g);
        gexp[idx*2+1] = sinf(g);
    }
}

// blocks [0,1536): propagate 24 chunk-groups (it 0..2 x c 0..7), 32 layers each,
//   1 row/wave. even c: forward -> S=Q^T ; odd c: reverse-transposed -> S=Q ;
//   c==7 seeds with gamma (S7=G*Q7). Output: compact complex planes (re,im) H+L.
// blocks [1536, 1536+8192): convert x_real/x_imag -> bf16 xbuf0 embedded rows.
__global__ void prop_conv_kernel(const float* __restrict__ coef,
                                 const float* __restrict__ gexp,
                                 const float* __restrict__ xre,
                                 const float* __restrict__ xim,
                                 unsigned short* __restrict__ chunkH,
                                 unsigned short* __restrict__ chunkL,
                                 unsigned short* __restrict__ xb)
{
    if (blockIdx.x >= PROPBLK) {
        int idx = (blockIdx.x - PROPBLK) * 256 + threadIdx.x;
        int b = idx >> 8, j = idx & 255;
        xb[(size_t)b * KDIM + j]       = f2bf(xre[idx]);
        xb[(size_t)b * KDIM + 256 + j] = f2bf(xim[idx]);
        return;
    }

    const int lane = threadIdx.x & 63;
    const int wv   = threadIdx.x >> 6;
    const int grp  = blockIdx.x >> 6;          // 0..23
    const int it   = grp >> 3, c = grp & 7;
    const int row  = (blockIdx.x & 63) * 4 + wv;
    const bool rev = (c & 1);

    float xr[4], xi[4];
    float gc = 1.0f, gs = 0.0f;
    if (c == 7) { gc = gexp[(it*NWG + row)*2]; gs = gexp[(it*NWG + row)*2 + 1]; }
#pragma unroll
    for (int e = 0; e < 4; ++e) {
        bool on = (4*lane + e) == row;
        xr[e] = on ? gc : 0.0f;
        xi[e] = on ? gs : 0.0f;
    }

    const float4* cb = (const float4*)coef + ((size_t)(it*NWG + c*CHL) * NPAIR) * 2;
    int sp0 = rev ? CHL-1 : 0;
    const float4* p = cb + ((size_t)sp0 * NPAIR + 2*lane) * 2;
    float4 c0a = p[0], c0b = p[1], c1a = p[2], c1b = p[3];

    for (int s = 0; s < CHL; ++s) {
        int sn  = (s + 1 < CHL) ? s + 1 : s;
        int spn = rev ? CHL-1 - sn : sn;
        const float4* np = cb + ((size_t)spn * NPAIR + 2*lane) * 2;
        float4 n0a = np[0], n0b = np[1], n1a = np[2], n1b = np[3];

        // rev chunks use the transposed 2x2: rows (A,C),(B,D)
        float4 u0a, u0b, u1a, u1b;
        if (rev) {
            u0a = make_float4(c0a.x, c0a.y, c0b.x, c0b.y);
            u0b = make_float4(c0a.z, c0a.w, c0b.z, c0b.w);
            u1a = make_float4(c1a.x, c1a.y, c1b.x, c1b.y);
            u1b = make_float4(c1a.z, c1a.w, c1b.z, c1b.w);
        } else {
            u0a = c0a; u0b = c0b; u1a = c1a; u1b = c1b;
        }

        int sp = rev ? CHL-1 - s : s;
        if ((sp & 1) == 0) {
            apply2(xr[0], xi[0], xr[1], xi[1], u0a, u0b);
            apply2(xr[2], xi[2], xr[3], xi[3], u1a, u1b);
        } else {
            float tr = __shfl_down(xr[0], 1, 64);
            float ti = __shfl_down(xi[0], 1, 64);
            apply2(xr[1], xi[1], xr[2], xi[2], u0a, u0b);
            float x3r = xr[3], x3i = xi[3];
            float y3r = u1a.x*x3r - u1a.y*x3i + u1a.z*tr - u1a.w*ti;
            float y3i = u1a.x*x3i + u1a.y*x3r + u1a.z*ti + u1a.w*tr;
            float ynr = u1b.x*x3r - u1b.y*x3i + u1b.z*tr - u1b.w*ti;
            float yni = u1b.x*x3i + u1b.y*x3r + u1b.z*ti + u1b.w*tr;
            float rr = __shfl_up(ynr, 1, 64);
            float ri = __shfl_up(yni, 1, 64);
            if (lane != 63) { xr[3] = y3r; xi[3] = y3i; }
            if (lane != 0)  { xr[0] = rr;  xi[0] = ri; }
        }
        c0a = n0a; c0b = n0b; c1a = n1a; c1b = n1b;
    }

    unsigned short* bh = chunkH + (size_t)grp * CMSZ;
    unsigned short* bl = chunkL + (size_t)grp * CMSZ;
    ushort4 reH, reL, imH, imL;
    unsigned short h, l;
#pragma unroll
    for (int e = 0; e < 4; ++e) {
        bsplit(xr[e], h, l); ((unsigned short*)&reH)[e] = h; ((unsigned short*)&reL)[e] = l;
        bsplit(xi[e], h, l); ((unsigned short*)&imH)[e] = h; ((unsigned short*)&imL)[e] = l;
    }
    *(ushort4*)(bh + (size_t)row*256 + 4*lane)         = reH;
    *(ushort4*)(bh + PLANE + (size_t)row*256 + 4*lane) = imH;
    *(ushort4*)(bl + (size_t)row*256 + 4*lane)         = reL;
    *(ushort4*)(bl + PLANE + (size_t)row*256 + 4*lane) = imL;
}

// Unified compose: C = Sa * Sb^T (complex, via real embedding built at staging).
// A staged plain-embedded ([Re|-Im],[Im|Re]); B staged conj ([Re|+Im], rows<256).
// Only left-half cols (n<256) of the embedded result computed (rest redundant).
// C = Ah*Bh^T + Ah*Bl^T + Al*Bh^T. level 0/1: out compact H+L ; level 2: bmat.
__global__ __launch_bounds__(256, 2) void compose_kernel(
    const unsigned short* __restrict__ srcH, const unsigned short* __restrict__ srcL,
    unsigned short* __restrict__ outH, unsigned short* __restrict__ outL,
    unsigned short* __restrict__ bmat, int level)
{
    __shared__ unsigned short sAh[2048], sAl[2048], sBh[2048], sBl[2048];
    const int z = blockIdx.z;
    int ai, bi;
    if (level == 0) {
        const int amap[4] = {0,3,4,7}, bmap[4] = {1,2,5,6};
        int it = z >> 2, j = z & 3;
        ai = it*NCHUNK + amap[j]; bi = it*NCHUNK + bmap[j];
    } else if (level == 1) {
        int it = z >> 1, wh = z & 1;
        ai = it*4 + (wh ? 3 : 0); bi = it*4 + (wh ? 2 : 1);
    } else {
        ai = 2*z + 1; bi = 2*z;
    }
    const int tid = threadIdx.x, lane = tid & 63, wv = tid >> 6;
    const int quad = lane >> 4, l16 = lane & 15;
    const int m0 = blockIdx.x * 64;          // embedded rows [0,512)
    const int n0 = blockIdx.y * 64;          // output complex cols [0,256)
    const bool isA = (wv < 2);
    const unsigned short* mat = ((wv & 1) ? srcL : srcH) + (size_t)(isA ? ai : bi) * CMSZ;
    unsigned short* dst = (wv==0)?sAh:(wv==1)?sAl:(wv==2)?sBh:sBl;
    const int l2 = lane >> 2, kq = (lane & 3) * 8;
    const int rowb = isA ? ((m0 < 256) ? m0 : m0 - 256) : n0;

    floatx4 acc[4] = {};
    for (int kt = 0; kt < KDIM; kt += 32) {
        // plane/sign uniform per (wave, kt):
        //  A, m0<256 : k<256 -> +re ; k>=256 -> -im
        //  A, m0>=256: k<256 -> +im ; k>=256 -> +re
        //  B (conj)  : k<256 -> +re ; k>=256 -> +im
        int po; bool neg = false;
        if (kt < 256) po = (isA && m0 >= 256) ? PLANE : 0;
        else {
            if (isA) { if (m0 < 256) { po = PLANE; neg = true; } else po = 0; }
            else po = PLANE;
        }
        int keff = (kt < 256 ? kt : kt - 256) + kq;
        const unsigned short* sp_ = mat + po;

        __syncthreads();
#pragma unroll
        for (int i = 0; i < 4; ++i) {
            int rl = i*16 + l2;
            uint4 v = *(const uint4*)(sp_ + (size_t)(rowb + rl)*256 + keff);
            if (neg) { v.x ^= 0x80008000u; v.y ^= 0x80008000u; v.z ^= 0x80008000u; v.w ^= 0x80008000u; }
            *(uint4*)(dst + rl*32 + kq) = v;
        }
        __syncthreads();

        short8 ah = *(const short8*)&sAh[(16*wv + l16)*32 + quad*8];
        short8 al = *(const short8*)&sAl[(16*wv + l16)*32 + quad*8];
#pragma unroll
        for (int ni = 0; ni < 4; ++ni) {
            short8 bh = *(const short8*)&sBh[(16*ni + l16)*32 + quad*8];
            short8 bl = *(const short8*)&sBl[(16*ni + l16)*32 + quad*8];
            acc[ni] = __builtin_amdgcn_mfma_f32_16x16x32_bf16(ah, bh, acc[ni], 0,0,0);
            acc[ni] = __builtin_amdgcn_mfma_f32_16x16x32_bf16(ah, bl, acc[ni], 0,0,0);
            acc[ni] = __builtin_amdgcn_mfma_f32_16x16x32_bf16(al, bh, acc[ni], 0,0,0);
        }
    }
#pragma unroll
    for (int ni = 0; ni < 4; ++ni)
#pragma unroll
        for (int rg = 0; rg < 4; ++rg) {
            int r = m0 + 16*wv + quad*4 + rg;    // embedded row
            int cc = n0 + 16*ni + l16;           // complex col (<256)
            float v = acc[ni][rg];
            if (level < 2) {
                unsigned short h, l; bsplit(v, h, l);
                size_t off = (size_t)z*CMSZ + ((r < 256) ? ((size_t)r*256 + cc)
                                                         : (PLANE + (size_t)(r-256)*256 + cc));
                outH[off] = h; outL[off] = l;
            } else {
                unsigned short* bm = bmat + (size_t)z*MSZ;
                if (r < 256) {          // Re(M)[r][cc]
                    unsigned short h = f2bf(v);
                    bm[(size_t)r*KDIM + cc] = h;
                    bm[(size_t)(r+256)*KDIM + cc + 256] = h;
                } else {                // Im(M)[r-256][cc]
                    bm[(size_t)r*KDIM + cc] = f2bf(v);
                    bm[(size_t)(r-256)*KDIM + cc + 256] = f2bf(-v);
                }
            }
        }
}

// out[b][n] = sum_k x[b][k]*Bm[n][k]. 64x128 tile (cols n0..n0+63 real rows +
// n0+256.. imag rows of embedded Bm). mode 0/1: EO nonlin -> bf16 ; 2: intensity.
__global__ __launch_bounds__(256, 2) void gemm_kernel(
    const unsigned short* __restrict__ A, const unsigned short* __restrict__ Bm,
    int mode, unsigned short* __restrict__ xout, float* __restrict__ Iout)
{
    __shared__ unsigned short sA[64*32];
    __shared__ unsigned short sB[128*32];
    const int tid = threadIdx.x, lane = tid & 63, wv = tid >> 6;
    const int quad = lane >> 4, l16 = lane & 15;
    const int m0 = blockIdx.x * 64, n0 = blockIdx.y * 64;
    const int trowb = lane >> 2, tcol = (lane & 3) * 8;

    floatx4 acc[8] = {};
    for (int kt = 0; kt < KDIM; kt += 32) {
        __syncthreads();
        async16(A + (size_t)(m0 + 16*wv + trowb)*KDIM + kt + tcol,
                &sA[wv*512 + lane*8]);
#pragma unroll
        for (int j = 0; j < 2; ++j) {
            int trow = 32*wv + 16*j + trowb;
            int grow = (trow < 64) ? (n0 + trow) : (n0 + trow + 192);
            async16(Bm + (size_t)grow*KDIM + kt + tcol,
                    &sB[(32*wv + 16*j)*32 + lane*8]);
        }
        __syncthreads();
        short8 a = *(const short8*)&sA[(16*wv + l16)*32 + quad*8];
#pragma unroll
        for (int ni = 0; ni < 8; ++ni) {
            short8 b = *(const short8*)&sB[(16*ni + l16)*32 + quad*8];
            acc[ni] = __builtin_amdgcn_mfma_f32_16x16x32_bf16(a, b, acc[ni], 0,0,0);
        }
    }
#pragma unroll
    for (int ni = 0; ni < 4; ++ni)
#pragma unroll
        for (int rg = 0; rg < 4; ++rg) {
            int row = m0 + 16*wv + quad*4 + rg;
            int cc  = n0 + 16*ni + l16;
            float yr = acc[ni][rg], yi = acc[ni+4][rg];
            if (mode == 2) {
                Iout[(size_t)row*256 + cc] = yr*yr + yi*yi;
            } else {
                float I = yr*yr + yi*yi;
                float phase = 0.078539816339744831f * I + 1.5707963267948966f;
                float sp, cp; __sincosf(phase, &sp, &cp);
                float f = 0.94868329805051381f * cp;
                xout[(size_t)row*KDIM + cc]       = f2bf(f*(cp*yr + sp*yi));
                xout[(size_t)row*KDIM + cc + 256] = f2bf(f*(cp*yi - sp*yr));
            }
        }
}

__global__ void final_kernel(const float* __restrict__ Ibuf,
                             float* __restrict__ out)
{
    const int lane = threadIdx.x & 63;
    const int wv   = threadIdx.x >> 6;
    const int row  = blockIdx.x * 4 + wv;
    float4 v = *(const float4*)(Ibuf + (size_t)row * 256 + 4*lane);
    float ss = v.x*v.x + v.y*v.y + v.z*v.z + v.w*v.w;
#pragma unroll
    for (int d = 1; d < 64; d <<= 1) ss += __shfl_xor(ss, d, 64);
    float inv = 1.0f / fmaxf(sqrtf(ss), 1e-12f);
    float* o = out + (size_t)row * 10;
    if (lane == 0)      { o[0]=v.x*inv; o[1]=v.y*inv; o[2]=v.z*inv; o[3]=v.w*inv; }
    else if (lane == 1) { o[4]=v.x*inv; o[5]=v.y*inv; o[6]=v.z*inv; o[7]=v.w*inv; }
    else if (lane == 2) { o[8]=v.x*inv; o[9]=v.y*inv; }
}

extern "C" void kernel_launch(void* const* d_in, const int* in_sizes, int n_in,
                              void* d_out, int out_size, void* d_ws, size_t ws_size,
                              hipStream_t stream)
{
    const float* x_real = (const float*)d_in[0];
    const float* x_imag = (const float*)d_in[1];
    const float* theta  = (const float*)d_in[2];
    const float* phi    = (const float*)d_in[3];
    const float* gamma  = (const float*)d_in[4];

    char* ws = (char*)d_ws;
    // lifetimes: coef[->prop] chunks[->lvl0] T[->lvl1] P[->lvl2] bmat[->gemm2]
    //            xbuf0[prop->gemm2] xbuf1[gemm0->gemm1] Ibuf[gemm2->final]
    float* coef  = (float*)(ws + 0);                              // 3 MB
    float* gexp  = (float*)(ws + 3145728);                        // 8 KB
    unsigned short* chunkH = (unsigned short*)(ws + 3153920);     // 6 MB
    unsigned short* chunkL = (unsigned short*)(ws + 9445376);     // 6 MB
    unsigned short* TL     = (unsigned short*)(ws + 15736832);    // 3 MB
    unsigned short* xbuf0  = (unsigned short*)(ws + 18882560);    // 8 MB -> peak 27.27 MB
    unsigned short* TH     = (unsigned short*)(ws + 0);           // 3 MB (alias coef)
    unsigned short* PH     = (unsigned short*)(ws + 3153920);     // 1.5 MB (alias chunkH)
    unsigned short* PL     = (unsigned short*)(ws + 4726784);     // 1.5 MB
    unsigned short* bmat   = (unsigned short*)(ws + 6299648);     // 1.5 MB
    unsigned short* xbuf1  = (unsigned short*)(ws + 7872512);     // 8 MB (alias chunkL+TL, dead)
    float* Ibuf            = (float*)(ws + 7872512);              // 8 MB (alias xbuf1)

    precompute_kernel<<<(NITER*NWG*NPAIR + 255)/256, 256, 0, stream>>>(
        theta, phi, gamma, coef, gexp);

    prop_conv_kernel<<<PROPBLK + NBATCH*NWG/256, 256, 0, stream>>>(
        coef, gexp, x_real, x_imag, chunkH, chunkL, xbuf0);

    compose_kernel<<<dim3(8,4,12), 256, 0, stream>>>(chunkH, chunkL, TH, TL, nullptr, 0);
    compose_kernel<<<dim3(8,4,6),  256, 0, stream>>>(TH, TL, PH, PL, nullptr, 1);
    compose_kernel<<<dim3(8,4,3),  256, 0, stream>>>(PH, PL, nullptr, nullptr, bmat, 2);

    gemm_kernel<<<dim3(128,4), 256, 0, stream>>>(xbuf0, bmat,           0, xbuf1, (float*)nullptr);
    gemm_kernel<<<dim3(128,4), 256, 0, stream>>>(xbuf1, bmat + MSZ,     1, xbuf0, (float*)nullptr);
    gemm_kernel<<<dim3(128,4), 256, 0, stream>>>(xbuf0, bmat + 2*MSZ,   2, (unsigned short*)nullptr, Ibuf);

    final_kernel<<<NBATCH/4, 256, 0, stream>>>(Ibuf, (float*)d_out);
}